// Round 9
// baseline (36.243 us; speedup 1.0000x reference)
//
#include <hip/hip_runtime.h>

// NSLayer: out = X + (-a*(X X^T) + b*(X X^T)^2) X per (b,c) slice, X: [512][64].
// Factored: G = X^T X (64x64), H = -a*G + b*G^2 (symmetric), out = X + X*H.
// bf16 MFMA (32x32x16), fp32 accumulate. 512 blocks x 512 threads, 2 blocks/CU.
// Round 9 (base = round 8):
//   * granule-XOR swizzle on ALL row-read LDS tiles (Xr/Gbf/Hbf, stride-72),
//     not just pass-1 Xt — kills the 8-way conflict on pass-2/3 MFMA reads
//     (measured 852K conflict-cycles ~= 1664/block, all from these reads)
//   * pass-3 computes o^T via operand swap (H symmetric): C/D regs map to 4
//     consecutive d per q-group -> float4 stores (64 dword -> 16 dwordx4) and
//     bf16x4 epilogue X-reads. Same products, same k-order: bit-identical.

typedef __bf16 bf16;
typedef __attribute__((ext_vector_type(8)))  __bf16 bf16x8;
typedef __attribute__((ext_vector_type(4)))  __bf16 bf16x4;
typedef __attribute__((ext_vector_type(16))) float  f32x16;

namespace {

__device__ __forceinline__ int sxz(int d) { return ((d >> 1) ^ (d >> 4)) & 7; }

// element offset into a [rows][72]bf16 tile, granule-XOR swizzled per row.
// g = 16B-granule index (col>>3); add (col&7) for scalars / 4*(col&7==4) etc.
__device__ __forceinline__ int rsw(int row, int g) {
    return row * 72 + ((g ^ sxz(row)) & 7) * 8;
}

__global__ __launch_bounds__(512, 2)
void ns_mfma(const float* __restrict__ inp, const float* __restrict__ aw,
             const float* __restrict__ bw, float* __restrict__ out) {
    // LDS map (72704 B, 2 blocks/CU):
    //   [0,36864):      pass1: Xt[half][buf] = 4 x 9216 ([64][72]bf16 each)
    //                   pass3: Xr0[128][72]bf16 + Xr1[128][72]bf16
    //   [36864,54272):  Gp[64][68]f32 partial
    //   [54272,63488):  Gbf[64][72]bf16 (swizzled)
    //   [63488,72704):  Hbf[64][72]bf16 (swizzled)
    __shared__ unsigned char smem[72704] __attribute__((aligned(128)));
    float* const Gp  = (float*)(smem + 36864);
    bf16*  const Gbf = (bf16*)(smem + 54272);
    bf16*  const Hbf = (bf16*)(smem + 63488);
    bf16*  const Xr0 = (bf16*)smem;
    bf16*  const Xr1 = (bf16*)(smem + 18432);

    const int slice = blockIdx.x;                // b*64 + c
    const float* __restrict__ X = inp + (size_t)slice * 32768;
    float* __restrict__ O       = out + (size_t)slice * 32768;

    const int t    = threadIdx.x;
    const int lane = t & 63;
    const int w    = t >> 6;       // wave 0..7
    const int l31  = lane & 31;
    const int l5   = lane >> 5;    // 0/1
    const int half = t >> 8;       // == w>>2
    const int th   = t & 255;
    const int s_nq = th >> 4;      // 0..15
    const int s_dq = th & 15;      // 0..15

    // half h owns chunks 4*(1-h)+s: half 1 owns pass-3 tiles 0,1 (pre-staged
    // in the G bubble); half 0 owns tiles 2,3 (staged inside pass-3).
    const float* __restrict__ Xbase =
        X + (size_t)(256 * (1 - half) + 4 * s_nq) * 64 + 4 * s_dq;

    // ====== Load entire X share into regs (once), convert to bf16 ==========
    bf16x4 xr[4][4];
    {
        float4 rv[4][4];
#pragma unroll
        for (int s = 0; s < 4; ++s)
#pragma unroll
            for (int rn = 0; rn < 4; ++rn)
                rv[s][rn] = *(const float4*)&Xbase[(size_t)(64 * s + rn) * 64];
#pragma unroll
        for (int s = 0; s < 4; ++s)
#pragma unroll
            for (int rn = 0; rn < 4; ++rn) {
                xr[s][rn][0] = (bf16)rv[s][rn].x;
                xr[s][rn][1] = (bf16)rv[s][rn].y;
                xr[s][rn][2] = (bf16)rv[s][rn].z;
                xr[s][rn][3] = (bf16)rv[s][rn].w;
            }
    }
    const float av = aw[slice & 63];
    const float bv = bw[slice & 63];

    // ================= Pass 1: G = X^T X, K-split across halves ============
    f32x16 acc;
#pragma unroll
    for (int q = 0; q < 16; ++q) acc[q] = 0.f;

    const int tile = w & 3;
    const int i32  = (tile >> 1) * 32;
    const int j32  = (tile & 1) * 32;
    const int rowA = i32 + l31;
    const int rowB = j32 + l31;

    unsigned char* const XtH = smem + half * 18432;   // this half's 2 buffers

#pragma unroll
    for (int it = 0; it < 4; ++it) {
        bf16* const Xt = (bf16*)(XtH + (it & 1) * 9216);
        // stage chunk (4*(1-half)+it) transposed, granule-swizzled
#pragma unroll
        for (int r = 0; r < 4; ++r) {
            const int d = 4 * s_dq + r;
            bf16x4 v;
            v[0] = xr[it][0][r]; v[1] = xr[it][1][r];
            v[2] = xr[it][2][r]; v[3] = xr[it][3][r];
            *(bf16x4*)&Xt[rsw(d, s_nq >> 1) + 4 * (s_nq & 1)] = v;
        }
        __syncthreads();   // single barrier/chunk (double-buffered Xt)
#pragma unroll
        for (int ks = 0; ks < 4; ++ks) {
            bf16x8 a = *(const bf16x8*)&Xt[rsw(rowA, 2 * ks + l5)];
            bf16x8 b = *(const bf16x8*)&Xt[rsw(rowB, 2 * ks + l5)];
            acc = __builtin_amdgcn_mfma_f32_32x32x16_bf16(a, b, acc, 0, 0, 0);
        }
    }
    __syncthreads();   // all pass-1 LDS reads done; Xt space now dead

    // ====== G bubble: half0 -> Gp; half1 pre-stages pass-3 tiles 0,1 =======
    if (half == 0) {
#pragma unroll
        for (int q = 0; q < 16; ++q) {
            const int r = (q & 3) + 8 * (q >> 2) + 4 * l5;   // C/D row (m74/m101)
            Gp[(i32 + r) * 68 + j32 + l31] = acc[q];
        }
    } else {
        // half1's xr[s] = chunk s = tile (s>>1), rows 64*(s&1)..+63
#pragma unroll
        for (int s = 0; s < 4; ++s) {
            bf16* const Xr = (s >> 1) ? Xr1 : Xr0;
            const int rowbase = 64 * (s & 1) + 4 * s_nq;
#pragma unroll
            for (int rn = 0; rn < 4; ++rn)
                *(bf16x4*)&Xr[rsw(rowbase + rn, s_dq >> 1) + 4 * (s_dq & 1)] = xr[s][rn];
        }
    }
    __syncthreads();
    if (half == 1) {
#pragma unroll
        for (int q = 0; q < 16; ++q) {
            const int r  = (q & 3) + 8 * (q >> 2) + 4 * l5;
            const int ii = i32 + r;
            const int jj = j32 + l31;
            Gbf[rsw(ii, jj >> 3) + (jj & 7)] = (bf16)(acc[q] + Gp[ii * 68 + jj]);
        }
    }
    __syncthreads();

    // ================= Pass 2: H = b*G^2 - a*G (waves 0-3) =================
    if (w < 4) {
        const int pi = (w >> 1) * 32;
        const int pj = (w & 1) * 32;
        f32x16 h;
#pragma unroll
        for (int q = 0; q < 16; ++q) h[q] = 0.f;
#pragma unroll
        for (int ks = 0; ks < 4; ++ks) {
            // G symmetric: both operands are row reads of Gbf
            bf16x8 a = *(const bf16x8*)&Gbf[rsw(pi + l31, 2 * ks + l5)];
            bf16x8 b = *(const bf16x8*)&Gbf[rsw(pj + l31, 2 * ks + l5)];
            h = __builtin_amdgcn_mfma_f32_32x32x16_bf16(a, b, h, 0, 0, 0);
        }
#pragma unroll
        for (int q = 0; q < 16; ++q) {
            const int r  = (q & 3) + 8 * (q >> 2) + 4 * l5;
            const int ii = pi + r;
            const int jj = pj + l31;
            const int o8 = rsw(ii, jj >> 3) + (jj & 7);
            Hbf[o8] = (bf16)(bv * h[q] - av * (float)Gbf[o8]);
        }
    }
    __syncthreads();   // Hbf ready; tiles 0,1 already staged

    // ====== Pass 3: o^T = H * X^T (H symmetric), ping-pong Xr ==============
    const int nb = (w >> 1) * 32;   // n-block within 128-row tile
    const int db = (w & 1) * 32;    // d-block

#pragma unroll
    for (int tt = 0; tt < 4; ++tt) {
        if (tt > 0) __syncthreads();
        if (half == 0 && (tt == 1 || tt == 2)) {
            // stage tile tt+1 into buf (tt+1)&1; half0's xr[s] = chunk 4+s
            bf16* const Xr = ((tt + 1) & 1) ? Xr1 : Xr0;
#pragma unroll
            for (int ss = 0; ss < 2; ++ss) {
                const int s       = 2 * (tt - 1) + ss;
                const int rowbase = 64 * ss + 4 * s_nq;
#pragma unroll
                for (int rn = 0; rn < 4; ++rn)
                    *(bf16x4*)&Xr[rsw(rowbase + rn, s_dq >> 1) + 4 * (s_dq & 1)] = xr[s][rn];
            }
        }
        const bf16* const Xr = (tt & 1) ? Xr1 : Xr0;

        f32x16 o;
#pragma unroll
        for (int q = 0; q < 16; ++q) o[q] = 0.f;
#pragma unroll
        for (int ks = 0; ks < 4; ++ks) {
            // A = H rows (d), B = X rows (n)  =>  C row(reg)=d, col(lane)=n
            bf16x8 a = *(const bf16x8*)&Hbf[rsw(db + l31, 2 * ks + l5)];
            bf16x8 b = *(const bf16x8*)&Xr [rsw(nb + l31, 2 * ks + l5)];
            o = __builtin_amdgcn_mfma_f32_32x32x16_bf16(a, b, o, 0, 0, 0);
        }
        // epilogue: out = X + X*H; 4 consecutive d per q-group -> float4 store
        {
            const int n = nb + l31;
            float* const orow = &O[(size_t)(tt * 128 + n) * 64];
#pragma unroll
            for (int qg = 0; qg < 4; ++qg) {
                const int d0 = db + 8 * qg + 4 * l5;
                const bf16x4 xv = *(const bf16x4*)&Xr[rsw(n, d0 >> 3) + (d0 & 7)];
                float4 ov;
                ov.x = o[4 * qg + 0] + (float)xv[0];
                ov.y = o[4 * qg + 1] + (float)xv[1];
                ov.z = o[4 * qg + 2] + (float)xv[2];
                ov.w = o[4 * qg + 3] + (float)xv[3];
                *(float4*)&orow[d0] = ov;
            }
        }
    }
}

}  // namespace

extern "C" void kernel_launch(void* const* d_in, const int* in_sizes, int n_in,
                              void* d_out, int out_size, void* d_ws, size_t ws_size,
                              hipStream_t stream) {
    const float* inp = (const float*)d_in[0];
    const float* aw  = (const float*)d_in[1];
    const float* bw  = (const float*)d_in[2];
    float* out       = (float*)d_out;

    ns_mfma<<<dim3(512), dim3(512), 0, stream>>>(inp, aw, bw, out);
}

// Round 10
// 25.393 us; speedup vs baseline: 1.4273x; 1.4273x over previous
//
#include <hip/hip_runtime.h>

// NSLayer: out = X + (-a*(X X^T) + b*(X X^T)^2) X per (b,c) slice, X: [512][64].
// Factored: G = X^T X (64x64), H = -a*G + b*G^2 (symmetric), out = X + X*H.
// bf16 MFMA (32x32x16), fp32 accumulate. 512 blocks x 512 threads, 2 blocks/CU.
// Round 10 = verbatim revert to round 8 (best measured: 25.41 us).
// Post-mortem of R9 (36.2 us): extra swizzle was solving a non-problem (R8's
// stride-72 row reads already hit the 8-access/bank wave64 minimum) and the
// operand-swapped epilogue broke store coalescing (32-B scattered segments
// vs R8's 128-B contiguous). Keep R8's structure:
//   * pass-1 Xt double-buffered: 1 barrier/chunk
//   * half h owns chunks 4*(1-h)+s: half-1 pre-stages pass-3 tiles 0,1 in
//     the G bubble; half-0 stages tiles 2,3 inside the pass-3 pipeline
//   * pass-3 ping-pong over 2 Xr buffers

typedef __bf16 bf16;
typedef __attribute__((ext_vector_type(8)))  __bf16 bf16x8;
typedef __attribute__((ext_vector_type(4)))  __bf16 bf16x4;
typedef __attribute__((ext_vector_type(16))) float  f32x16;

namespace {

__device__ __forceinline__ int sxz(int d) { return ((d >> 1) ^ (d >> 4)) & 7; }

__global__ __launch_bounds__(512, 2)
void ns_mfma(const float* __restrict__ inp, const float* __restrict__ aw,
             const float* __restrict__ bw, float* __restrict__ out) {
    // LDS map (72704 B, 2 blocks/CU):
    //   [0,36864):      pass1: Xt[half][buf] = 4 x 9216 ([64][72]bf16 each)
    //                   pass3: Xr0[128][72]bf16 (=[0,18432)) + Xr1 (=[18432,36864))
    //   [36864,54272):  Gp[64][68]f32 partial
    //   [54272,63488):  Gbf[64][72]bf16
    //   [63488,72704):  Hbf[64][72]bf16
    __shared__ unsigned char smem[72704] __attribute__((aligned(128)));
    float* const Gp  = (float*)(smem + 36864);
    bf16*  const Gbf = (bf16*)(smem + 54272);
    bf16*  const Hbf = (bf16*)(smem + 63488);
    bf16*  const Xr0 = (bf16*)smem;
    bf16*  const Xr1 = (bf16*)(smem + 18432);

    const int slice = blockIdx.x;                // b*64 + c
    const float* __restrict__ X = inp + (size_t)slice * 32768;
    float* __restrict__ O       = out + (size_t)slice * 32768;

    const int t    = threadIdx.x;
    const int lane = t & 63;
    const int w    = t >> 6;       // wave 0..7
    const int l31  = lane & 31;
    const int l5   = lane >> 5;    // 0/1
    const int half = t >> 8;       // == w>>2
    const int th   = t & 255;
    const int s_nq = th >> 4;      // 0..15
    const int s_dq = th & 15;      // 0..15

    // half h owns chunks 4*(1-h)+s, s=0..3 (rows 256*(1-h)+64*s+4*s_nq+rn).
    // => half 1 owns chunks 0..3 = pass-3 tiles 0,1 (pre-staged in G bubble);
    //    half 0 owns chunks 4..7 = tiles 2,3 (staged during pass-3 pipeline).
    const float* __restrict__ Xbase =
        X + (size_t)(256 * (1 - half) + 4 * s_nq) * 64 + 4 * s_dq;

    // ====== Load entire X share into regs (once), convert to bf16 ==========
    bf16x4 xr[4][4];
    {
        float4 rv[4][4];
#pragma unroll
        for (int s = 0; s < 4; ++s)
#pragma unroll
            for (int rn = 0; rn < 4; ++rn)
                rv[s][rn] = *(const float4*)&Xbase[(size_t)(64 * s + rn) * 64];
#pragma unroll
        for (int s = 0; s < 4; ++s)
#pragma unroll
            for (int rn = 0; rn < 4; ++rn) {
                xr[s][rn][0] = (bf16)rv[s][rn].x;
                xr[s][rn][1] = (bf16)rv[s][rn].y;
                xr[s][rn][2] = (bf16)rv[s][rn].z;
                xr[s][rn][3] = (bf16)rv[s][rn].w;
            }
    }
    const float av = aw[slice & 63];
    const float bv = bw[slice & 63];

    // ================= Pass 1: G = X^T X, K-split across halves ============
    f32x16 acc;
#pragma unroll
    for (int q = 0; q < 16; ++q) acc[q] = 0.f;

    const int tile = w & 3;
    const int i32  = (tile >> 1) * 32;
    const int j32  = (tile & 1) * 32;
    const int rowA = i32 + l31;
    const int rowB = j32 + l31;
    const int sA   = sxz(rowA);
    const int sB   = sxz(rowB);

    unsigned char* const XtH = smem + half * 18432;   // this half's 2 buffers

#pragma unroll
    for (int it = 0; it < 4; ++it) {
        bf16* const Xt = (bf16*)(XtH + (it & 1) * 9216);
        // stage chunk (4*(1-half)+it) transposed, 16B-granule swizzled
#pragma unroll
        for (int r = 0; r < 4; ++r) {
            const int d = 4 * s_dq + r;
            bf16x4 v;
            v[0] = xr[it][0][r]; v[1] = xr[it][1][r];
            v[2] = xr[it][2][r]; v[3] = xr[it][3][r];
            const int g = ((s_nq >> 1) ^ sxz(d)) & 7;
            *(bf16x4*)&Xt[d * 72 + g * 8 + 4 * (s_nq & 1)] = v;
        }
        __syncthreads();   // single barrier/chunk (double-buffered Xt)
#pragma unroll
        for (int ks = 0; ks < 4; ++ks) {
            const int gw = 2 * ks + l5;
            bf16x8 a = *(const bf16x8*)&Xt[rowA * 72 + ((gw ^ sA) & 7) * 8];
            bf16x8 b = *(const bf16x8*)&Xt[rowB * 72 + ((gw ^ sB) & 7) * 8];
            acc = __builtin_amdgcn_mfma_f32_32x32x16_bf16(a, b, acc, 0, 0, 0);
        }
    }
    __syncthreads();   // B0: all pass-1 LDS reads done; Xt space now dead

    // ====== G bubble: half0 -> Gp; half1 pre-stages pass-3 tiles 0,1 =======
    if (half == 0) {
#pragma unroll
        for (int q = 0; q < 16; ++q) {
            const int r = (q & 3) + 8 * (q >> 2) + 4 * l5;   // C/D row (m74/m101)
            Gp[(i32 + r) * 68 + j32 + l31] = acc[q];
        }
    } else {
        // half1's xr[s] = chunk s = tile (s>>1), rows 64*(s&1)..+63
#pragma unroll
        for (int s = 0; s < 4; ++s) {
            bf16* const Xr = (s >> 1) ? Xr1 : Xr0;
            const int rowbase = 64 * (s & 1) + 4 * s_nq;
#pragma unroll
            for (int rn = 0; rn < 4; ++rn)
                *(bf16x4*)&Xr[(rowbase + rn) * 72 + 4 * s_dq] = xr[s][rn];
        }
    }
    __syncthreads();   // B1
    if (half == 1) {
#pragma unroll
        for (int q = 0; q < 16; ++q) {
            const int r  = (q & 3) + 8 * (q >> 2) + 4 * l5;
            const int ii = i32 + r;
            const int jj = j32 + l31;
            Gbf[ii * 72 + jj] = (bf16)(acc[q] + Gp[ii * 68 + jj]);
        }
    }
    __syncthreads();   // B2

    // ================= Pass 2: H = b*G^2 - a*G (waves 0-3) =================
    if (w < 4) {
        const int pi = (w >> 1) * 32;
        const int pj = (w & 1) * 32;
        f32x16 h;
#pragma unroll
        for (int q = 0; q < 16; ++q) h[q] = 0.f;
#pragma unroll
        for (int ks = 0; ks < 4; ++ks) {
            // G symmetric: both operands are row reads of Gbf
            bf16x8 a = *(const bf16x8*)&Gbf[(pi + l31) * 72 + ks * 16 + 8 * l5];
            bf16x8 b = *(const bf16x8*)&Gbf[(pj + l31) * 72 + ks * 16 + 8 * l5];
            h = __builtin_amdgcn_mfma_f32_32x32x16_bf16(a, b, h, 0, 0, 0);
        }
#pragma unroll
        for (int q = 0; q < 16; ++q) {
            const int r  = (q & 3) + 8 * (q >> 2) + 4 * l5;
            const int ii = pi + r;
            const int jj = pj + l31;
            Hbf[ii * 72 + jj] = (bf16)(bv * h[q] - av * (float)Gbf[ii * 72 + jj]);
        }
    }
    __syncthreads();   // B3: Hbf ready; tiles 0,1 already staged

    // ================= Pass 3: out = X + X*H, ping-pong Xr =================
    const int nb = (w >> 1) * 32;   // n-block within 128-row tile
    const int db = (w & 1) * 32;    // d-block

#pragma unroll
    for (int tt = 0; tt < 4; ++tt) {
        if (tt > 0) __syncthreads();   // B4/B5/B6
        if (half == 0 && (tt == 1 || tt == 2)) {
            // stage tile tt+1 into buf (tt+1)&1; half0's xr[s] = chunk 4+s
            bf16* const Xr = ((tt + 1) & 1) ? Xr1 : Xr0;
#pragma unroll
            for (int ss = 0; ss < 2; ++ss) {
                const int s       = 2 * (tt - 1) + ss;
                const int rowbase = 64 * ss + 4 * s_nq;
#pragma unroll
                for (int rn = 0; rn < 4; ++rn)
                    *(bf16x4*)&Xr[(rowbase + rn) * 72 + 4 * s_dq] = xr[s][rn];
            }
        }
        const bf16* const Xr = (tt & 1) ? Xr1 : Xr0;

        f32x16 o;
#pragma unroll
        for (int q = 0; q < 16; ++q) o[q] = 0.f;
#pragma unroll
        for (int ks = 0; ks < 4; ++ks) {
            bf16x8 a = *(const bf16x8*)&Xr [(nb + l31) * 72 + ks * 16 + 8 * l5];
            bf16x8 b = *(const bf16x8*)&Hbf[(db + l31) * 72 + ks * 16 + 8 * l5];
            o = __builtin_amdgcn_mfma_f32_32x32x16_bf16(a, b, o, 0, 0, 0);
        }
        // epilogue: out = X + X*H; 128B-contiguous dword stores
#pragma unroll
        for (int q = 0; q < 16; ++q) {
            const int rl = (q & 3) + 8 * (q >> 2) + 4 * l5;
            const int nl = nb + rl;
            const int d  = db + l31;
            O[(size_t)(tt * 128 + nl) * 64 + d] = o[q] + (float)Xr[nl * 72 + d];
        }
    }
}

}  // namespace

extern "C" void kernel_launch(void* const* d_in, const int* in_sizes, int n_in,
                              void* d_out, int out_size, void* d_ws, size_t ws_size,
                              hipStream_t stream) {
    const float* inp = (const float*)d_in[0];
    const float* aw  = (const float*)d_in[1];
    const float* bw  = (const float*)d_in[2];
    float* out       = (float*)d_out;

    ns_mfma<<<dim3(512), dim3(512), 0, stream>>>(inp, aw, bw, out);
}